// Round 14
// baseline (98.528 us; speedup 1.0000x reference)
//
#include <hip/hip_runtime.h>
#include <hip/hip_bf16.h>

// MaskedDenseLayerMultiMasks: out[b,m,o] = sum_i x[b,m,i] * kernel[i,o] * masks[m,i,o]
// Round 14: prep recoalesced at the INSTRUCTION level + X-pass deleted.
//   mdl_prep_w: 1 granule/thread: 16 scalar loads (256B-contig/instr), one
//     16B store with lanes sweeping col (1KB-contig/instr). No partial lines.
//   mdl_gemm2: barrier-free fragment GEMM (r12/r13, ~L2-roofline). A-frags
//     now built from RAW f32 X (2x f32x4 + cvt_pk per granule) -- removes the
//     scatter-heavy Xp pass entirely. B-path/loop/epilogue unchanged.

#define BATCH 512
#define NMASK 16
#define IN_D  1024
#define OUT_D 1024

using bf16x8 = __attribute__((ext_vector_type(8))) __bf16;
using bf16x4 = __attribute__((ext_vector_type(4))) __bf16;
using f32x16 = __attribute__((ext_vector_type(16))) float;
using f32x4  = __attribute__((ext_vector_type(4))) float;
using f32x2  = __attribute__((ext_vector_type(2))) float;

typedef const __attribute__((address_space(1))) void gvoid_t;
typedef __attribute__((address_space(3))) void lvoid_t;

__device__ __forceinline__ void dma16(const void* g, const void* l) {
    __builtin_amdgcn_global_load_lds((gvoid_t*)(uintptr_t)g,
                                     (lvoid_t*)(uintptr_t)l, 16, 0, 0);
}

// ===================== pass 1: W = Kn*Mk -> bf16 granules ====================
// Wt granule (m, G, col) at elem ((m*128+G)*1024+col)*8, j holds k=G*8+j.
// Block = (m, G, cq): col = cq*256 + t. Per thread: 16 scalar loads (lanes
// sweep col: 256B contiguous per instruction), 1x 16B store (lanes sweep col:
// 1KB contiguous per instruction).
__global__ void __launch_bounds__(256, 8)
mdl_prep_w(const float* __restrict__ Kn,
           const float* __restrict__ Mk,
           unsigned short* __restrict__ Wt)
{
    const int raw = blockIdx.x;                      // 8192 blocks
    const int wg  = (raw & 7) * 1024 + (raw >> 3);   // XCD-bijective
    const int m  = wg >> 9;          // 0..15
    const int G  = (wg >> 2) & 127;  // 0..127
    const int cq = wg & 3;           // 0..3
    const int col = cq * 256 + threadIdx.x;
    const int i0  = G * 8;

    const float* mk = Mk + ((size_t)m * IN_D + i0) * OUT_D + col;
    const float* kn = Kn + (size_t)i0 * OUT_D + col;

    float a[8], b[8];
#pragma unroll
    for (int r = 0; r < 8; ++r) {
        a[r] = mk[(size_t)r * OUT_D];
        b[r] = kn[(size_t)r * OUT_D];
    }
    bf16x8 g;
#pragma unroll
    for (int r = 0; r < 8; ++r)
        g[r] = (__bf16)(a[r] * b[r]);

    *(bf16x8*)(Wt + (((size_t)m * 128 + G) * 1024 + col) * 8) = g;
}

// =================== pass 2: barrier-free fragment GEMM =====================
struct Frags { bf16x8 a[2][2]; bf16x8 b[2][2]; };   // [s][ti] / [s][tj]

__global__ void __launch_bounds__(256, 2)
mdl_gemm2(const float* __restrict__ X,
          const unsigned short* __restrict__ Wt,
          float* __restrict__ Out)
{
    const int t = threadIdx.x;
    const int l = t & 63;
    const int w = t >> 6;              // wave 0..3

    const int raw = blockIdx.x;        // 512 blocks
    const int wg  = (raw & 7) * 64 + (raw >> 3);   // XCD-bijective
    const int v   = wg * 4 + w;        // global wave 0..2047
    const int m   = v >> 7;            // 0..15
    const int v7  = v & 127;
    const int bt  = v7 >> 4;           // 0..7   (64-row strip)
    const int ot  = v7 & 15;           // 0..15  (64-col strip)

    const int ls = l >> 5;             // k-half of the 32x32x16 frag
    const int bcol = ot * 64 + (l & 31);

    // raw-X base for this lane's A row (ti adds 32 rows = 32*16*1024 floats)
    const float* Xb = X + ((size_t)(bt * 64 + (l & 31)) * NMASK + m) * IN_D;

    f32x16 acc[2][2];
#pragma unroll
    for (int ti = 0; ti < 2; ++ti)
#pragma unroll
        for (int tj = 0; tj < 2; ++tj)
#pragma unroll
            for (int e = 0; e < 16; ++e)
                acc[ti][tj][e] = 0.f;

    auto LOADF = [&](Frags& F, int kb) {
#pragma unroll
        for (int s = 0; s < 2; ++s) {
            const int G = (kb >> 3) + s * 2 + ls;           // k-octet index
#pragma unroll
            for (int ti = 0; ti < 2; ++ti) {
                const float* ap = Xb + (size_t)ti * (32 * NMASK * IN_D) + G * 8;
                f32x4 x0 = *(const f32x4*)(ap);
                f32x4 x1 = *(const f32x4*)(ap + 4);
                bf16x8 af;
#pragma unroll
                for (int j = 0; j < 4; ++j) {
                    af[j]     = (__bf16)x0[j];
                    af[4 + j] = (__bf16)x1[j];
                }
                F.a[s][ti] = af;
            }
            const unsigned short* bb =
                Wt + (((size_t)m * 128 + G) * 1024 + bcol) * 8;
            F.b[s][0] = *(const bf16x8*)(bb);
            F.b[s][1] = *(const bf16x8*)(bb + 256);         // tj=1: +32 cols
        }
    };
    auto MF = [&](Frags& F) {
#pragma unroll
        for (int s = 0; s < 2; ++s)
#pragma unroll
            for (int ti = 0; ti < 2; ++ti)
#pragma unroll
                for (int tj = 0; tj < 2; ++tj)
                    acc[ti][tj] = __builtin_amdgcn_mfma_f32_32x32x16_bf16(
                        F.a[s][ti], F.b[s][tj], acc[ti][tj], 0, 0, 0);
    };

    Frags S0, S1;                       // named sets (rule #20)
    LOADF(S0, 0);
    for (int kb = 0; kb < IN_D; kb += 64) {
        LOADF(S1, kb + 32);
        __builtin_amdgcn_sched_barrier(0);   // keep prefetch above MFMA cluster
        MF(S0);                              // dataflow wait = counted vmcnt
        LOADF(S0, (kb + 64) & (IN_D - 1));   // tail wraps to 0 (harmless)
        __builtin_amdgcn_sched_barrier(0);
        MF(S1);
    }

    // epilogue: C/D 32x32 layout (r7/r12-verified): col=l&31, row=g*8+q+4*(l>>5)
    const int r0 = bt * 64 + 4 * ls;
    const int c0 = ot * 64 + (l & 31);
#pragma unroll
    for (int ti = 0; ti < 2; ++ti) {
#pragma unroll
        for (int tj = 0; tj < 2; ++tj) {
#pragma unroll
            for (int g = 0; g < 4; ++g) {
#pragma unroll
                for (int q = 0; q < 4; ++q) {
                    const int row = r0 + ti * 32 + g * 8 + q;
                    const int col = c0 + tj * 32;
                    Out[((size_t)row * NMASK + m) * OUT_D + col] =
                        acc[ti][tj][g * 4 + q];
                }
            }
        }
    }
}

// ================= fallback (r9 fused kernel) for small ws ==================
#define FAKP 40
#define FBKP 34
#define FMFSZ (32 * 128)

__global__ void __launch_bounds__(512, 4)
mdl_fused_fallback(const float* __restrict__ X,
                   const float* __restrict__ Kn,
                   const float* __restrict__ Mk,
                   float* __restrict__ Out)
{
    __shared__ __align__(16) float          Mf[3 * FMFSZ];
    __shared__ __align__(16) unsigned short As[128 * FAKP];
    __shared__ __align__(16) unsigned short Bs[128 * FBKP];

    const int t = threadIdx.x;
    const int l = t & 63;
    const int w = t >> 6;

    const int raw = blockIdx.x;
    const int wg  = (raw & 7) * 64 + (raw >> 3);
    const int m   = wg >> 5;
    const int ob  = (wg >> 2) & 7;
    const int bb  = wg & 3;

    const int wr = w >> 2, wc = w & 3;

    f32x4 acc[4][2];
#pragma unroll
    for (int mi = 0; mi < 4; ++mi)
#pragma unroll
        for (int ni = 0; ni < 2; ++ni)
            acc[mi][ni] = (f32x4){0.f, 0.f, 0.f, 0.f};

    const int a_row = t >> 2;
    const int a_kh  = (t & 3) * 8;
    const int o2 = (t & 63) * 2;
    const int k4 = w * 4;

    const int obase = ob * 128;
    const float* Xa  = X + ((size_t)(bb * 128 + a_row) * NMASK + m) * IN_D + a_kh;
    const float* Knb = Kn + obase + o2;
    const float* Mkm = Mk + (size_t)m * IN_D * OUT_D;

    auto DMA = [&](int tile, int c) {
        const int kt = tile * 32;
#pragma unroll
        for (int j = 0; j < 2; ++j) {
            const int k = j * 16 + w * 2 + (l >> 5);
            const float* gsrc = Mkm + (size_t)(kt + k) * OUT_D + obase + (l & 31) * 4;
            dma16(gsrc, &Mf[c * FMFSZ + j * 2048 + w * 256]);
        }
    };

    DMA(0, 0);
    DMA(1, 1);
    asm volatile("s_waitcnt vmcnt(2)" ::: "memory");
    __builtin_amdgcn_sched_barrier(0);
    __builtin_amdgcn_s_barrier();
    __builtin_amdgcn_sched_barrier(0);

    int c_cur = 0, c_nxt = 1, c_far = 2;

    for (int tt = 0; tt < 32; ++tt) {
        const int kt = tt * 32;
        f32x4 xv0 = *(const f32x4*)(Xa + kt);
        f32x4 xv1 = *(const f32x4*)(Xa + kt + 4);
        f32x2 kv[4];
#pragma unroll
        for (int r = 0; r < 4; ++r)
            kv[r] = *(const f32x2*)(Knb + (size_t)(kt + k4 + r) * OUT_D);
        __builtin_amdgcn_sched_barrier(0);
        DMA((tt + 2 < 32) ? tt + 2 : 0, c_far);
        __builtin_amdgcn_sched_barrier(0);
        {
            f32x2 mvv[4];
#pragma unroll
            for (int r = 0; r < 4; ++r)
                mvv[r] = *(const f32x2*)(&Mf[c_cur * FMFSZ + (k4 + r) * 128 + o2]);
#pragma unroll
            for (int c = 0; c < 2; ++c) {
                bf16x4 vv;
#pragma unroll
                for (int r = 0; r < 4; ++r)
                    vv[r] = (__bf16)(kv[r][c] * mvv[r][c]);
                *(bf16x4*)(&Bs[(o2 + c) * FBKP + k4]) = vv;
            }
            bf16x8 va;
#pragma unroll
            for (int j = 0; j < 4; ++j) {
                va[j] = (__bf16)xv0[j]; va[4 + j] = (__bf16)xv1[j];
            }
            *(bf16x8*)(&As[a_row * FAKP + a_kh]) = va;
        }
        asm volatile("s_waitcnt lgkmcnt(0)" ::: "memory");
        __builtin_amdgcn_sched_barrier(0);
        __builtin_amdgcn_s_barrier();
        __builtin_amdgcn_sched_barrier(0);
        {
            const int kg = (l >> 4) * 8;
            bf16x8 bfv[2];
#pragma unroll
            for (int ni = 0; ni < 2; ++ni) {
                const int n = wc * 32 + ni * 16 + (l & 15);
                bf16x4 lo = *(const bf16x4*)(&Bs[n * FBKP + kg]);
                bf16x4 hi = *(const bf16x4*)(&Bs[n * FBKP + kg + 4]);
                bf16x8 f;
                f[0] = lo[0]; f[1] = lo[1]; f[2] = lo[2]; f[3] = lo[3];
                f[4] = hi[0]; f[5] = hi[1]; f[6] = hi[2]; f[7] = hi[3];
                bfv[ni] = f;
            }
#pragma unroll
            for (int mi = 0; mi < 4; ++mi) {
                const int r = wr * 64 + mi * 16 + (l & 15);
                bf16x8 af = *(const bf16x8*)(&As[r * FAKP + kg]);
#pragma unroll
                for (int ni = 0; ni < 2; ++ni)
                    acc[mi][ni] = __builtin_amdgcn_mfma_f32_16x16x32_bf16(
                        af, bfv[ni], acc[mi][ni], 0, 0, 0);
            }
        }
        asm volatile("s_waitcnt vmcnt(2)" ::: "memory");
        __builtin_amdgcn_sched_barrier(0);
        __builtin_amdgcn_s_barrier();
        __builtin_amdgcn_sched_barrier(0);
        const int tmp = c_cur; c_cur = c_nxt; c_nxt = c_far; c_far = tmp;
    }
    asm volatile("s_waitcnt vmcnt(0)" ::: "memory");

    const int r0 = bb * 128 + wr * 64 + (l >> 4) * 4;
    const int c0 = ob * 128 + wc * 32 + (l & 15);
#pragma unroll
    for (int mi = 0; mi < 4; ++mi) {
#pragma unroll
        for (int j = 0; j < 4; ++j) {
            const size_t row = (size_t)(r0 + mi * 16 + j);
            float* op = Out + (row * NMASK + m) * OUT_D + c0;
#pragma unroll
            for (int ni = 0; ni < 2; ++ni)
                op[ni * 16] = acc[mi][ni][j];
        }
    }
}

extern "C" void kernel_launch(void* const* d_in, const int* in_sizes, int n_in,
                              void* d_out, int out_size, void* d_ws, size_t ws_size,
                              hipStream_t stream) {
    (void)in_sizes; (void)n_in; (void)out_size;
    const float* X  = (const float*)d_in[0];
    const float* Kn = (const float*)d_in[1];
    const float* Mk = (const float*)d_in[2];
    float* Out = (float*)d_out;

    const size_t w_bytes = (size_t)NMASK * IN_D * OUT_D * sizeof(unsigned short); // 32 MiB

    if (ws_size >= w_bytes) {
        unsigned short* Wt = (unsigned short*)d_ws;
        mdl_prep_w<<<8192, 256, 0, stream>>>(Kn, Mk, Wt);
        mdl_gemm2<<<512, 256, 0, stream>>>(X, Wt, Out);
    } else {
        mdl_fused_fallback<<<512, 512, 0, stream>>>(X, Kn, Mk, Out);
    }
}

// Round 15
// 61.454 us; speedup vs baseline: 1.6033x; 1.6033x over previous
//
#include <hip/hip_runtime.h>
#include <hip/hip_bf16.h>

// MaskedDenseLayerMultiMasks: out[b,m,o] = sum_i x[b,m,i] * kernel[i,o] * masks[m,i,o]
// Round 15: recombination of measured-best pieces.
//   mdl_prep_w (r14, ~15us): W=Kn*Mk -> bf16 granules; 256B-contig reads,
//     1KB-contig stores per instruction.
//   mdl_prep_x (r12/r13, small): X -> bf16 A-granule strips (Xp).
//   mdl_gemm2 (r13, ~14.8us = L2 roofline): barrier-free fragment GEMM from
//     Xp + Wt. No LDS, no barriers, 2048 independent waves.

#define BATCH 512
#define NMASK 16
#define IN_D  1024
#define OUT_D 1024

using bf16x8 = __attribute__((ext_vector_type(8))) __bf16;
using bf16x4 = __attribute__((ext_vector_type(4))) __bf16;
using f32x16 = __attribute__((ext_vector_type(16))) float;
using f32x4  = __attribute__((ext_vector_type(4))) float;
using f32x2  = __attribute__((ext_vector_type(2))) float;

typedef const __attribute__((address_space(1))) void gvoid_t;
typedef __attribute__((address_space(3))) void lvoid_t;

__device__ __forceinline__ void dma16(const void* g, const void* l) {
    __builtin_amdgcn_global_load_lds((gvoid_t*)(uintptr_t)g,
                                     (lvoid_t*)(uintptr_t)l, 16, 0, 0);
}

// ===================== pass 1a: W = Kn*Mk -> bf16 granules ===================
// Wt granule (m, G, col) at elem ((m*128+G)*1024+col)*8, j holds k=G*8+j.
// Per thread: 16 scalar loads (256B contiguous per instruction across lanes),
// one 16B store (lanes sweep col -> 1KB contiguous per instruction).
__global__ void __launch_bounds__(256, 8)
mdl_prep_w(const float* __restrict__ Kn,
           const float* __restrict__ Mk,
           unsigned short* __restrict__ Wt)
{
    const int raw = blockIdx.x;                      // 8192 blocks
    const int wg  = (raw & 7) * 1024 + (raw >> 3);   // XCD-bijective
    const int m  = wg >> 9;          // 0..15
    const int G  = (wg >> 2) & 127;  // 0..127
    const int cq = wg & 3;           // 0..3
    const int col = cq * 256 + threadIdx.x;
    const int i0  = G * 8;

    const float* mk = Mk + ((size_t)m * IN_D + i0) * OUT_D + col;
    const float* kn = Kn + (size_t)i0 * OUT_D + col;

    float a[8], b[8];
#pragma unroll
    for (int r = 0; r < 8; ++r) {
        a[r] = mk[(size_t)r * OUT_D];
        b[r] = kn[(size_t)r * OUT_D];
    }
    bf16x8 g;
#pragma unroll
    for (int r = 0; r < 8; ++r)
        g[r] = (__bf16)(a[r] * b[r]);

    *(bf16x8*)(Wt + (((size_t)m * 128 + G) * 1024 + col) * 8) = g;
}

// ===================== pass 1b: X -> bf16 granule strips =====================
// Xp[strip=m*8+bt]: elem G*512 + row*8 + j = bf16 X[bt*64+row][m][G*8+j].
// (r12/r13-verified.)
__global__ void __launch_bounds__(512, 4)
mdl_prep_x(const float* __restrict__ X,
           unsigned short* __restrict__ Xp)
{
    const int t  = threadIdx.x;
    const int b2 = blockIdx.x;           // 0..511
    const int strip = b2 >> 2;           // 0..127 = m*8+bt
    const int Gq    = b2 & 3;
    const int m  = strip >> 3;
    const int bt = strip & 7;
    const int row = t >> 3;              // 0..63
    const int oc  = t & 7;

    const float* src = X + ((size_t)(bt * 64 + row) * NMASK + m) * IN_D
                         + Gq * 256 + oc * 32;
    f32x4 av[8];
#pragma unroll
    for (int q = 0; q < 8; ++q)
        av[q] = *(const f32x4*)(src + q * 4);

    unsigned short* dstS = Xp + (size_t)strip * 65536
                              + (size_t)(Gq * 32 + oc * 4) * 512 + row * 8;
#pragma unroll
    for (int j = 0; j < 4; ++j) {
        bf16x8 g;
#pragma unroll
        for (int e = 0; e < 4; ++e) {
            g[e]     = (__bf16)av[2 * j][e];
            g[4 + e] = (__bf16)av[2 * j + 1][e];
        }
        *(bf16x8*)(dstS + (size_t)j * 512) = g;
    }
}

// =================== pass 2: barrier-free fragment GEMM =====================
struct Frags { bf16x8 a[2][2]; bf16x8 b[2][2]; };   // [s][ti] / [s][tj]

__global__ void __launch_bounds__(256, 2)
mdl_gemm2(const unsigned short* __restrict__ Xp,
          const unsigned short* __restrict__ Wt,
          float* __restrict__ Out)
{
    const int t = threadIdx.x;
    const int l = t & 63;
    const int w = t >> 6;              // wave 0..3

    const int raw = blockIdx.x;        // 512 blocks
    const int wg  = (raw & 7) * 64 + (raw >> 3);   // XCD-bijective
    const int v   = wg * 4 + w;        // global wave 0..2047
    const int m   = v >> 7;            // 0..15
    const int v7  = v & 127;
    const int bt  = v7 >> 4;           // 0..7   (64-row strip)
    const int ot  = v7 & 15;           // 0..15  (64-col strip)

    const unsigned short* Ap = Xp + (size_t)(m * 8 + bt) * 65536;
    const int la = (l & 31) * 8;       // lane granule offset (elems)
    const int ls = l >> 5;             // k-half of the 32x32x16 frag
    const int bcol = ot * 64 + (l & 31);

    f32x16 acc[2][2];
#pragma unroll
    for (int ti = 0; ti < 2; ++ti)
#pragma unroll
        for (int tj = 0; tj < 2; ++tj)
#pragma unroll
            for (int e = 0; e < 16; ++e)
                acc[ti][tj][e] = 0.f;

    auto LOADF = [&](Frags& F, int kb) {
#pragma unroll
        for (int s = 0; s < 2; ++s) {
            const int G = (kb >> 3) + s * 2 + ls;           // k-octet index
            const unsigned short* ab = Ap + (size_t)G * 512 + la;
            F.a[s][0] = *(const bf16x8*)(ab);
            F.a[s][1] = *(const bf16x8*)(ab + 256);         // ti=1: +32 rows
            const unsigned short* bb =
                Wt + (((size_t)m * 128 + G) * 1024 + bcol) * 8;
            F.b[s][0] = *(const bf16x8*)(bb);
            F.b[s][1] = *(const bf16x8*)(bb + 256);         // tj=1: +32 cols
        }
    };
    auto MF = [&](Frags& F) {
#pragma unroll
        for (int s = 0; s < 2; ++s)
#pragma unroll
            for (int ti = 0; ti < 2; ++ti)
#pragma unroll
                for (int tj = 0; tj < 2; ++tj)
                    acc[ti][tj] = __builtin_amdgcn_mfma_f32_32x32x16_bf16(
                        F.a[s][ti], F.b[s][tj], acc[ti][tj], 0, 0, 0);
    };

    Frags S0, S1;                       // named sets (rule #20)
    LOADF(S0, 0);
    for (int kb = 0; kb < IN_D; kb += 64) {
        LOADF(S1, kb + 32);
        __builtin_amdgcn_sched_barrier(0);   // keep prefetch above MFMA cluster
        MF(S0);                              // dataflow wait = counted vmcnt
        LOADF(S0, (kb + 64) & (IN_D - 1));   // tail wraps to 0 (harmless)
        __builtin_amdgcn_sched_barrier(0);
        MF(S1);
    }

    // epilogue: C/D 32x32 layout (r7/r12-verified): col=l&31, row=g*8+q+4*(l>>5)
    const int r0 = bt * 64 + 4 * ls;
    const int c0 = ot * 64 + (l & 31);
#pragma unroll
    for (int ti = 0; ti < 2; ++ti) {
#pragma unroll
        for (int tj = 0; tj < 2; ++tj) {
#pragma unroll
            for (int g = 0; g < 4; ++g) {
#pragma unroll
                for (int q = 0; q < 4; ++q) {
                    const int row = r0 + ti * 32 + g * 8 + q;
                    const int col = c0 + tj * 32;
                    Out[((size_t)row * NMASK + m) * OUT_D + col] =
                        acc[ti][tj][g * 4 + q];
                }
            }
        }
    }
}

// ================= fallback (r9 fused kernel) for small ws ==================
#define FAKP 40
#define FBKP 34
#define FMFSZ (32 * 128)

__global__ void __launch_bounds__(512, 4)
mdl_fused_fallback(const float* __restrict__ X,
                   const float* __restrict__ Kn,
                   const float* __restrict__ Mk,
                   float* __restrict__ Out)
{
    __shared__ __align__(16) float          Mf[3 * FMFSZ];
    __shared__ __align__(16) unsigned short As[128 * FAKP];
    __shared__ __align__(16) unsigned short Bs[128 * FBKP];

    const int t = threadIdx.x;
    const int l = t & 63;
    const int w = t >> 6;

    const int raw = blockIdx.x;
    const int wg  = (raw & 7) * 64 + (raw >> 3);
    const int m   = wg >> 5;
    const int ob  = (wg >> 2) & 7;
    const int bb  = wg & 3;

    const int wr = w >> 2, wc = w & 3;

    f32x4 acc[4][2];
#pragma unroll
    for (int mi = 0; mi < 4; ++mi)
#pragma unroll
        for (int ni = 0; ni < 2; ++ni)
            acc[mi][ni] = (f32x4){0.f, 0.f, 0.f, 0.f};

    const int a_row = t >> 2;
    const int a_kh  = (t & 3) * 8;
    const int o2 = (t & 63) * 2;
    const int k4 = w * 4;

    const int obase = ob * 128;
    const float* Xa  = X + ((size_t)(bb * 128 + a_row) * NMASK + m) * IN_D + a_kh;
    const float* Knb = Kn + obase + o2;
    const float* Mkm = Mk + (size_t)m * IN_D * OUT_D;

    auto DMA = [&](int tile, int c) {
        const int kt = tile * 32;
#pragma unroll
        for (int j = 0; j < 2; ++j) {
            const int k = j * 16 + w * 2 + (l >> 5);
            const float* gsrc = Mkm + (size_t)(kt + k) * OUT_D + obase + (l & 31) * 4;
            dma16(gsrc, &Mf[c * FMFSZ + j * 2048 + w * 256]);
        }
    };

    DMA(0, 0);
    DMA(1, 1);
    asm volatile("s_waitcnt vmcnt(2)" ::: "memory");
    __builtin_amdgcn_sched_barrier(0);
    __builtin_amdgcn_s_barrier();
    __builtin_amdgcn_sched_barrier(0);

    int c_cur = 0, c_nxt = 1, c_far = 2;

    for (int tt = 0; tt < 32; ++tt) {
        const int kt = tt * 32;
        f32x4 xv0 = *(const f32x4*)(Xa + kt);
        f32x4 xv1 = *(const f32x4*)(Xa + kt + 4);
        f32x2 kv[4];
#pragma unroll
        for (int r = 0; r < 4; ++r)
            kv[r] = *(const f32x2*)(Knb + (size_t)(kt + k4 + r) * OUT_D);
        __builtin_amdgcn_sched_barrier(0);
        DMA((tt + 2 < 32) ? tt + 2 : 0, c_far);
        __builtin_amdgcn_sched_barrier(0);
        {
            f32x2 mvv[4];
#pragma unroll
            for (int r = 0; r < 4; ++r)
                mvv[r] = *(const f32x2*)(&Mf[c_cur * FMFSZ + (k4 + r) * 128 + o2]);
#pragma unroll
            for (int c = 0; c < 2; ++c) {
                bf16x4 vv;
#pragma unroll
                for (int r = 0; r < 4; ++r)
                    vv[r] = (__bf16)(kv[r][c] * mvv[r][c]);
                *(bf16x4*)(&Bs[(o2 + c) * FBKP + k4]) = vv;
            }
            bf16x8 va;
#pragma unroll
            for (int j = 0; j < 4; ++j) {
                va[j] = (__bf16)xv0[j]; va[4 + j] = (__bf16)xv1[j];
            }
            *(bf16x8*)(&As[a_row * FAKP + a_kh]) = va;
        }
        asm volatile("s_waitcnt lgkmcnt(0)" ::: "memory");
        __builtin_amdgcn_sched_barrier(0);
        __builtin_amdgcn_s_barrier();
        __builtin_amdgcn_sched_barrier(0);
        {
            const int kg = (l >> 4) * 8;
            bf16x8 bfv[2];
#pragma unroll
            for (int ni = 0; ni < 2; ++ni) {
                const int n = wc * 32 + ni * 16 + (l & 15);
                bf16x4 lo = *(const bf16x4*)(&Bs[n * FBKP + kg]);
                bf16x4 hi = *(const bf16x4*)(&Bs[n * FBKP + kg + 4]);
                bf16x8 f;
                f[0] = lo[0]; f[1] = lo[1]; f[2] = lo[2]; f[3] = lo[3];
                f[4] = hi[0]; f[5] = hi[1]; f[6] = hi[2]; f[7] = hi[3];
                bfv[ni] = f;
            }
#pragma unroll
            for (int mi = 0; mi < 4; ++mi) {
                const int r = wr * 64 + mi * 16 + (l & 15);
                bf16x8 af = *(const bf16x8*)(&As[r * FAKP + kg]);
#pragma unroll
                for (int ni = 0; ni < 2; ++ni)
                    acc[mi][ni] = __builtin_amdgcn_mfma_f32_16x16x32_bf16(
                        af, bfv[ni], acc[mi][ni], 0, 0, 0);
            }
        }
        asm volatile("s_waitcnt vmcnt(2)" ::: "memory");
        __builtin_amdgcn_sched_barrier(0);
        __builtin_amdgcn_s_barrier();
        __builtin_amdgcn_sched_barrier(0);
        const int tmp = c_cur; c_cur = c_nxt; c_nxt = c_far; c_far = tmp;
    }
    asm volatile("s_waitcnt vmcnt(0)" ::: "memory");

    const int r0 = bb * 128 + wr * 64 + (l >> 4) * 4;
    const int c0 = ob * 128 + wc * 32 + (l & 15);
#pragma unroll
    for (int mi = 0; mi < 4; ++mi) {
#pragma unroll
        for (int j = 0; j < 4; ++j) {
            const size_t row = (size_t)(r0 + mi * 16 + j);
            float* op = Out + (row * NMASK + m) * OUT_D + c0;
#pragma unroll
            for (int ni = 0; ni < 2; ++ni)
                op[ni * 16] = acc[mi][ni][j];
        }
    }
}

extern "C" void kernel_launch(void* const* d_in, const int* in_sizes, int n_in,
                              void* d_out, int out_size, void* d_ws, size_t ws_size,
                              hipStream_t stream) {
    (void)in_sizes; (void)n_in; (void)out_size;
    const float* X  = (const float*)d_in[0];
    const float* Kn = (const float*)d_in[1];
    const float* Mk = (const float*)d_in[2];
    float* Out = (float*)d_out;

    const size_t w_bytes = (size_t)NMASK * IN_D * OUT_D * sizeof(unsigned short); // 32 MiB
    const size_t x_bytes = (size_t)BATCH * NMASK * IN_D * sizeof(unsigned short); // 16 MiB

    if (ws_size >= w_bytes + x_bytes) {
        unsigned short* Wt = (unsigned short*)d_ws;
        unsigned short* Xp = (unsigned short*)d_ws + w_bytes / 2;
        mdl_prep_w<<<8192, 256, 0, stream>>>(Kn, Mk, Wt);
        mdl_prep_x<<<512, 512, 0, stream>>>(X, Xp);
        mdl_gemm2<<<512, 256, 0, stream>>>(Xp, Wt, Out);
    } else {
        mdl_fused_fallback<<<512, 512, 0, stream>>>(X, Kn, Mk, Out);
    }
}

// Round 16
// 54.125 us; speedup vs baseline: 1.8204x; 1.1354x over previous
//
#include <hip/hip_runtime.h>
#include <hip/hip_bf16.h>

// MaskedDenseLayerMultiMasks: out[b,m,o] = sum_i x[b,m,i] * kernel[i,o] * masks[m,i,o]
// Round 16: 2-dispatch version of r15 with prep_x store-scatter fixed.
//   mdl_prep (merged): W-blocks = r14's proven 1KB-contig pattern; X-blocks
//     now LDS-transpose so store instructions are 1KB-contiguous (lane=row).
//     Block-range split via raw%9 keeps X-blocks spread over all XCDs.
//   mdl_gemm2 (r13/r15, verified): barrier-free fragment GEMM, ~L2 roofline.

#define BATCH 512
#define NMASK 16
#define IN_D  1024
#define OUT_D 1024

using bf16x8 = __attribute__((ext_vector_type(8))) __bf16;
using bf16x4 = __attribute__((ext_vector_type(4))) __bf16;
using f32x16 = __attribute__((ext_vector_type(16))) float;
using f32x4  = __attribute__((ext_vector_type(4))) float;
using f32x2  = __attribute__((ext_vector_type(2))) float;

typedef const __attribute__((address_space(1))) void gvoid_t;
typedef __attribute__((address_space(3))) void lvoid_t;

__device__ __forceinline__ void dma16(const void* g, const void* l) {
    __builtin_amdgcn_global_load_lds((gvoid_t*)(uintptr_t)g,
                                     (lvoid_t*)(uintptr_t)l, 16, 0, 0);
}

// ============================ pass 1: prep ==================================
// raw = 9q+r. r<8 -> W-block wg2 = 8q+r (4096 blocks): (m, G, ch); 1KB-contig
// reads and stores per instruction (r14-proven).
// r==8 -> X-block q (512 blocks): (strip, Gq); coalesced loads -> LDS[64][264]
// -> barrier -> lane=row stores (1KB contiguous per instruction).
// Xp layout (r12-verified): strip=m*8+bt; elem G*512+row*8+j =
//   bf16 X[bt*64+row][m][G*8+j].
__global__ void __launch_bounds__(512, 4)
mdl_prep(const float* __restrict__ X,
         const float* __restrict__ Kn,
         const float* __restrict__ Mk,
         unsigned short* __restrict__ Wt,
         unsigned short* __restrict__ Xp)
{
    __shared__ __align__(16) unsigned short Ls[64 * 264];   // 33 KiB (X-blocks)

    const int t   = threadIdx.x;
    const int raw = blockIdx.x;          // 4608 blocks
    const int q   = raw / 9;
    const int r9  = raw - q * 9;

    if (r9 < 8) {
        // ---------------- W-part ----------------
        const int wg2 = q * 8 + r9;      // 0..4095
        const int m  = wg2 >> 8;         // 0..15
        const int G  = (wg2 >> 1) & 127; // 0..127
        const int ch = wg2 & 1;          // 0..1
        const int col = ch * 512 + t;
        const int i0  = G * 8;

        const float* mk = Mk + ((size_t)m * IN_D + i0) * OUT_D + col;
        const float* kn = Kn + (size_t)i0 * OUT_D + col;

        float a[8], b[8];
#pragma unroll
        for (int rr = 0; rr < 8; ++rr) {
            a[rr] = mk[(size_t)rr * OUT_D];
            b[rr] = kn[(size_t)rr * OUT_D];
        }
        bf16x8 g;
#pragma unroll
        for (int rr = 0; rr < 8; ++rr)
            g[rr] = (__bf16)(a[rr] * b[rr]);

        *(bf16x8*)(Wt + (((size_t)m * 128 + G) * 1024 + col) * 8) = g;
    } else {
        // ---------------- X-part ----------------
        const int strip = q >> 2;        // 0..127 = m*8+bt
        const int Gq    = q & 3;         // k-quarter
        const int m  = strip >> 3;
        const int bt = strip & 7;
        const int row = t >> 3;          // 0..63
        const int oc  = t & 7;           // 0..7

        // coalesced-ish loads: 128B contiguous per thread
        const float* src = X + ((size_t)(bt * 64 + row) * NMASK + m) * IN_D
                             + Gq * 256 + oc * 32;
        f32x4 av[8];
#pragma unroll
        for (int qq = 0; qq < 8; ++qq)
            av[qq] = *(const f32x4*)(src + qq * 4);

        // convert -> LDS granules [row][gl], padded row stride 264 elems
#pragma unroll
        for (int j = 0; j < 4; ++j) {
            bf16x8 g;
#pragma unroll
            for (int e = 0; e < 4; ++e) {
                g[e]     = (__bf16)av[2 * j][e];
                g[4 + e] = (__bf16)av[2 * j + 1][e];
            }
            *(bf16x8*)(&Ls[row * 264 + (oc * 4 + j) * 8]) = g;
        }

        __syncthreads();

        // store: wave w owns 4 granule-columns; lane = row -> per instruction
        // 64 lanes x 16B = 1KB contiguous in Xp
        const int w = t >> 6;            // 0..7
        const int l = t & 63;            // row
        unsigned short* dstS = Xp + (size_t)strip * 65536
                                  + (size_t)(Gq * 32 + w * 4) * 512 + l * 8;
#pragma unroll
        for (int u = 0; u < 4; ++u) {
            bf16x8 g = *(const bf16x8*)(&Ls[l * 264 + (w * 4 + u) * 8]);
            *(bf16x8*)(dstS + (size_t)u * 512) = g;
        }
    }
}

// =================== pass 2: barrier-free fragment GEMM =====================
struct Frags { bf16x8 a[2][2]; bf16x8 b[2][2]; };   // [s][ti] / [s][tj]

__global__ void __launch_bounds__(256, 2)
mdl_gemm2(const unsigned short* __restrict__ Xp,
          const unsigned short* __restrict__ Wt,
          float* __restrict__ Out)
{
    const int t = threadIdx.x;
    const int l = t & 63;
    const int w = t >> 6;              // wave 0..3

    const int raw = blockIdx.x;        // 512 blocks
    const int wg  = (raw & 7) * 64 + (raw >> 3);   // XCD-bijective
    const int v   = wg * 4 + w;        // global wave 0..2047
    const int m   = v >> 7;            // 0..15
    const int v7  = v & 127;
    const int bt  = v7 >> 4;           // 0..7   (64-row strip)
    const int ot  = v7 & 15;           // 0..15  (64-col strip)

    const unsigned short* Ap = Xp + (size_t)(m * 8 + bt) * 65536;
    const int la = (l & 31) * 8;       // lane granule offset (elems)
    const int ls = l >> 5;             // k-half of the 32x32x16 frag
    const int bcol = ot * 64 + (l & 31);

    f32x16 acc[2][2];
#pragma unroll
    for (int ti = 0; ti < 2; ++ti)
#pragma unroll
        for (int tj = 0; tj < 2; ++tj)
#pragma unroll
            for (int e = 0; e < 16; ++e)
                acc[ti][tj][e] = 0.f;

    auto LOADF = [&](Frags& F, int kb) {
#pragma unroll
        for (int s = 0; s < 2; ++s) {
            const int G = (kb >> 3) + s * 2 + ls;           // k-octet index
            const unsigned short* ab = Ap + (size_t)G * 512 + la;
            F.a[s][0] = *(const bf16x8*)(ab);
            F.a[s][1] = *(const bf16x8*)(ab + 256);         // ti=1: +32 rows
            const unsigned short* bb =
                Wt + (((size_t)m * 128 + G) * 1024 + bcol) * 8;
            F.b[s][0] = *(const bf16x8*)(bb);
            F.b[s][1] = *(const bf16x8*)(bb + 256);         // tj=1: +32 cols
        }
    };
    auto MF = [&](Frags& F) {
#pragma unroll
        for (int s = 0; s < 2; ++s)
#pragma unroll
            for (int ti = 0; ti < 2; ++ti)
#pragma unroll
                for (int tj = 0; tj < 2; ++tj)
                    acc[ti][tj] = __builtin_amdgcn_mfma_f32_32x32x16_bf16(
                        F.a[s][ti], F.b[s][tj], acc[ti][tj], 0, 0, 0);
    };

    Frags S0, S1;                       // named sets (rule #20)
    LOADF(S0, 0);
    for (int kb = 0; kb < IN_D; kb += 64) {
        LOADF(S1, kb + 32);
        __builtin_amdgcn_sched_barrier(0);   // keep prefetch above MFMA cluster
        MF(S0);                              // dataflow wait = counted vmcnt
        LOADF(S0, (kb + 64) & (IN_D - 1));   // tail wraps to 0 (harmless)
        __builtin_amdgcn_sched_barrier(0);
        MF(S1);
    }

    // epilogue: C/D 32x32 layout (r7/r12-verified): col=l&31, row=g*8+q+4*(l>>5)
    const int r0 = bt * 64 + 4 * ls;
    const int c0 = ot * 64 + (l & 31);
#pragma unroll
    for (int ti = 0; ti < 2; ++ti) {
#pragma unroll
        for (int tj = 0; tj < 2; ++tj) {
#pragma unroll
            for (int g = 0; g < 4; ++g) {
#pragma unroll
                for (int qq = 0; qq < 4; ++qq) {
                    const int row = r0 + ti * 32 + g * 8 + qq;
                    const int col = c0 + tj * 32;
                    Out[((size_t)row * NMASK + m) * OUT_D + col] =
                        acc[ti][tj][g * 4 + qq];
                }
            }
        }
    }
}

// ================= fallback (r9 fused kernel) for small ws ==================
#define FAKP 40
#define FBKP 34
#define FMFSZ (32 * 128)

__global__ void __launch_bounds__(512, 4)
mdl_fused_fallback(const float* __restrict__ X,
                   const float* __restrict__ Kn,
                   const float* __restrict__ Mk,
                   float* __restrict__ Out)
{
    __shared__ __align__(16) float          Mf[3 * FMFSZ];
    __shared__ __align__(16) unsigned short As[128 * FAKP];
    __shared__ __align__(16) unsigned short Bs[128 * FBKP];

    const int t = threadIdx.x;
    const int l = t & 63;
    const int w = t >> 6;

    const int raw = blockIdx.x;
    const int wg  = (raw & 7) * 64 + (raw >> 3);
    const int m   = wg >> 5;
    const int ob  = (wg >> 2) & 7;
    const int bb  = wg & 3;

    const int wr = w >> 2, wc = w & 3;

    f32x4 acc[4][2];
#pragma unroll
    for (int mi = 0; mi < 4; ++mi)
#pragma unroll
        for (int ni = 0; ni < 2; ++ni)
            acc[mi][ni] = (f32x4){0.f, 0.f, 0.f, 0.f};

    const int a_row = t >> 2;
    const int a_kh  = (t & 3) * 8;
    const int o2 = (t & 63) * 2;
    const int k4 = w * 4;

    const int obase = ob * 128;
    const float* Xa  = X + ((size_t)(bb * 128 + a_row) * NMASK + m) * IN_D + a_kh;
    const float* Knb = Kn + obase + o2;
    const float* Mkm = Mk + (size_t)m * IN_D * OUT_D;

    auto DMA = [&](int tile, int c) {
        const int kt = tile * 32;
#pragma unroll
        for (int j = 0; j < 2; ++j) {
            const int k = j * 16 + w * 2 + (l >> 5);
            const float* gsrc = Mkm + (size_t)(kt + k) * OUT_D + obase + (l & 31) * 4;
            dma16(gsrc, &Mf[c * FMFSZ + j * 2048 + w * 256]);
        }
    };

    DMA(0, 0);
    DMA(1, 1);
    asm volatile("s_waitcnt vmcnt(2)" ::: "memory");
    __builtin_amdgcn_sched_barrier(0);
    __builtin_amdgcn_s_barrier();
    __builtin_amdgcn_sched_barrier(0);

    int c_cur = 0, c_nxt = 1, c_far = 2;

    for (int tt = 0; tt < 32; ++tt) {
        const int kt = tt * 32;
        f32x4 xv0 = *(const f32x4*)(Xa + kt);
        f32x4 xv1 = *(const f32x4*)(Xa + kt + 4);
        f32x2 kv[4];
#pragma unroll
        for (int rr = 0; rr < 4; ++rr)
            kv[rr] = *(const f32x2*)(Knb + (size_t)(kt + k4 + rr) * OUT_D);
        __builtin_amdgcn_sched_barrier(0);
        DMA((tt + 2 < 32) ? tt + 2 : 0, c_far);
        __builtin_amdgcn_sched_barrier(0);
        {
            f32x2 mvv[4];
#pragma unroll
            for (int rr = 0; rr < 4; ++rr)
                mvv[rr] = *(const f32x2*)(&Mf[c_cur * FMFSZ + (k4 + rr) * 128 + o2]);
#pragma unroll
            for (int c = 0; c < 2; ++c) {
                bf16x4 vv;
#pragma unroll
                for (int rr = 0; rr < 4; ++rr)
                    vv[rr] = (__bf16)(kv[rr][c] * mvv[rr][c]);
                *(bf16x4*)(&Bs[(o2 + c) * FBKP + k4]) = vv;
            }
            bf16x8 va;
#pragma unroll
            for (int j = 0; j < 4; ++j) {
                va[j] = (__bf16)xv0[j]; va[4 + j] = (__bf16)xv1[j];
            }
            *(bf16x8*)(&As[a_row * FAKP + a_kh]) = va;
        }
        asm volatile("s_waitcnt lgkmcnt(0)" ::: "memory");
        __builtin_amdgcn_sched_barrier(0);
        __builtin_amdgcn_s_barrier();
        __builtin_amdgcn_sched_barrier(0);
        {
            const int kg = (l >> 4) * 8;
            bf16x8 bfv[2];
#pragma unroll
            for (int ni = 0; ni < 2; ++ni) {
                const int n = wc * 32 + ni * 16 + (l & 15);
                bf16x4 lo = *(const bf16x4*)(&Bs[n * FBKP + kg]);
                bf16x4 hi = *(const bf16x4*)(&Bs[n * FBKP + kg + 4]);
                bf16x8 f;
                f[0] = lo[0]; f[1] = lo[1]; f[2] = lo[2]; f[3] = lo[3];
                f[4] = hi[0]; f[5] = hi[1]; f[6] = hi[2]; f[7] = hi[3];
                bfv[ni] = f;
            }
#pragma unroll
            for (int mi = 0; mi < 4; ++mi) {
                const int rr = wr * 64 + mi * 16 + (l & 15);
                bf16x8 af = *(const bf16x8*)(&As[rr * FAKP + kg]);
#pragma unroll
                for (int ni = 0; ni < 2; ++ni)
                    acc[mi][ni] = __builtin_amdgcn_mfma_f32_16x16x32_bf16(
                        af, bfv[ni], acc[mi][ni], 0, 0, 0);
            }
        }
        asm volatile("s_waitcnt vmcnt(2)" ::: "memory");
        __builtin_amdgcn_sched_barrier(0);
        __builtin_amdgcn_s_barrier();
        __builtin_amdgcn_sched_barrier(0);
        const int tmp = c_cur; c_cur = c_nxt; c_nxt = c_far; c_far = tmp;
    }
    asm volatile("s_waitcnt vmcnt(0)" ::: "memory");

    const int r0 = bb * 128 + wr * 64 + (l >> 4) * 4;
    const int c0 = ob * 128 + wc * 32 + (l & 15);
#pragma unroll
    for (int mi = 0; mi < 4; ++mi) {
#pragma unroll
        for (int j = 0; j < 4; ++j) {
            const size_t row = (size_t)(r0 + mi * 16 + j);
            float* op = Out + (row * NMASK + m) * OUT_D + c0;
#pragma unroll
            for (int ni = 0; ni < 2; ++ni)
                op[ni * 16] = acc[mi][ni][j];
        }
    }
}

extern "C" void kernel_launch(void* const* d_in, const int* in_sizes, int n_in,
                              void* d_out, int out_size, void* d_ws, size_t ws_size,
                              hipStream_t stream) {
    (void)in_sizes; (void)n_in; (void)out_size;
    const float* X  = (const float*)d_in[0];
    const float* Kn = (const float*)d_in[1];
    const float* Mk = (const float*)d_in[2];
    float* Out = (float*)d_out;

    const size_t w_bytes = (size_t)NMASK * IN_D * OUT_D * sizeof(unsigned short); // 32 MiB
    const size_t x_bytes = (size_t)BATCH * NMASK * IN_D * sizeof(unsigned short); // 16 MiB

    if (ws_size >= w_bytes + x_bytes) {
        unsigned short* Wt = (unsigned short*)d_ws;
        unsigned short* Xp = (unsigned short*)d_ws + w_bytes / 2;
        mdl_prep<<<4608, 512, 0, stream>>>(X, Kn, Mk, Wt, Xp);
        mdl_gemm2<<<512, 256, 0, stream>>>(Xp, Wt, Out);
    } else {
        mdl_fused_fallback<<<512, 512, 0, stream>>>(X, Kn, Mk, Out);
    }
}